// Round 6
// baseline (514.619 us; speedup 1.0000x reference)
//
#include <hip/hip_runtime.h>
#include <hip/hip_bf16.h>
#include <hip/hip_fp16.h>

// ============================================================================
// MinGRUCell forward, MI355X (gfx950).  Round 6.
//   zh = x @ W^T + b     (x,W rounded to bf16, MFMA GEMM, global_load_lds)
//   h[t] = sigmoid(-z)*h[t-1] + sigmoid(z)*g(h_inter), h[-1]=hx  (linear scan)
//
// Round-5: 477 us, absmax 0.031. Scan phases ran at ~2.8 TB/s effective --
// TLP/latency-bound at 2 blocks/CU, not width-bound. This round:
//   - NCHUNK 128->256 (CLEN=16): 1024 blocks = 4/CU = 16 waves/CU in p1/p3.
//   - Full unroll of the 16-step loop (all loads hoistable ahead of the
//     dependent gate chain; round-5's unroll-4 capped in-flight loads).
//   - Non-temporal stores for p3's 134 MB out stream: keeps zbuf+hbuf
//     (128 MiB) LLC-resident for p3's second read, no write-allocate pollution.
//   - seed stored fp16 (4 MiB) so ws stays at the proven 136 MiB.
//
// ws (136 MiB): wb bf16 4 | zbuf fp16 64 | hbuf fp16 64 | seed fp16 4
// d_out scratch until p3: xb bf16 [0,64Mi) | Aar [64,72Mi) | Bar [72,80Mi)
// ============================================================================

#define N_B   8
#define L_SEQ 4096
#define H_DIM 1024
#define K_DIM 1024
#define O_DIM 2048
#define M_TOT (N_B * L_SEQ)      // 32768 GEMM rows

#define BM 128
#define BN 128
#define BK 64

#define NCHUNK 256
#define CLEN   (L_SEQ / NCHUNK)  // 16
#define NCH    (N_B * H_DIM)     // 8192 channels

typedef unsigned short ushort_t;
typedef unsigned short us8 __attribute__((ext_vector_type(8)));
typedef __bf16 v8bf __attribute__((ext_vector_type(8)));
typedef float f32x4 __attribute__((ext_vector_type(4)));

static __device__ __forceinline__ ushort_t f2bf(float f) {
    __hip_bfloat16 h = __float2bfloat16(f);   // RTN
    return *reinterpret_cast<ushort_t*>(&h);
}

// async global->LDS DMA, 16B per lane, LDS dest = wave-uniform base + lane*16
static __device__ __forceinline__ void dma16(const ushort_t* g, ushort_t* l) {
    __builtin_amdgcn_global_load_lds(
        (const __attribute__((address_space(1))) unsigned int*)g,
        (__attribute__((address_space(3))) unsigned int*)l,
        16, 0, 0);
}

// ---------------------------------------------------------------------------
// fp32 -> bf16 (8 elems/thread)
// ---------------------------------------------------------------------------
__global__ __launch_bounds__(256) void cvt_f32_bf16(
    const float* __restrict__ src, ushort_t* __restrict__ dst)
{
    const int i = blockIdx.x * 256 + threadIdx.x;
    const float4 f0 = ((const float4*)src)[2 * i];
    const float4 f1 = ((const float4*)src)[2 * i + 1];
    us8 o;
    o[0] = f2bf(f0.x); o[1] = f2bf(f0.y); o[2] = f2bf(f0.z); o[3] = f2bf(f0.w);
    o[4] = f2bf(f1.x); o[5] = f2bf(f1.y); o[6] = f2bf(f1.z); o[7] = f2bf(f1.w);
    ((us8*)dst)[i] = o;
}

// ---------------------------------------------------------------------------
// GEMM (unchanged since round 3: m97-plateau, ~859 TF, 157 us).
// C[m,o] = sum_k xb[m,k]*Wb[o,k] + b[o]; 128x128 tile, 4 waves,
// mfma_f32_16x16x32_bf16, global_load_lds dwordx4 staging, XOR swizzle on the
// global source address side (DMA dest is wave-uniform base + lane*16).
// ---------------------------------------------------------------------------
__global__ __launch_bounds__(256) void gemm_zh(
    const ushort_t* __restrict__ Xb,       // (M_TOT, K) bf16 bits
    const ushort_t* __restrict__ Wb,       // (O_DIM, K) bf16 bits
    const float* __restrict__ bias,        // (O_DIM) fp32
    __half* __restrict__ zbuf,             // (M_TOT, H_DIM) fp16
    __half* __restrict__ hbuf)             // (M_TOT, H_DIM) fp16
{
    __shared__ ushort_t As[BM * BK];
    __shared__ ushort_t Bs[BN * BK];

    const int tid    = threadIdx.x;
    const int wave   = tid >> 6;
    const int lane   = tid & 63;
    const int lane15 = lane & 15;
    const int quad   = lane >> 4;

    const int n0 = blockIdx.x * BN;        // O-tile fast -> A-tile L2 reuse
    const int m0 = blockIdx.y * BM;

    const int lrow = lane >> 3;            // 0..7
    const int jj   = (lane & 7) ^ lrow;    // global chunk (xor swizzle)
    const ushort_t* gA = Xb + (size_t)(m0 + wave * 8 + lrow) * K_DIM + jj * 8;
    const ushort_t* gB = Wb + (size_t)(n0 + wave * 8 + lrow) * K_DIM + jj * 8;
    ushort_t* lA = &As[(wave * 8) * BK];
    ushort_t* lB = &Bs[(wave * 8) * BK];

    const int wm = (wave >> 1) * 64;
    const int wn = (wave & 1) * 64;

    int offA[2][4], offB[2][4];
#pragma unroll
    for (int s = 0; s < 2; ++s) {
#pragma unroll
        for (int t = 0; t < 4; ++t) {
            const int rowA = wm + t * 16 + lane15;
            offA[s][t] = rowA * BK + (((s * 4 + quad) ^ (rowA & 7)) * 8);
            const int rowB = wn + t * 16 + lane15;
            offB[s][t] = rowB * BK + (((s * 4 + quad) ^ (rowB & 7)) * 8);
        }
    }

    const f32x4 fzero = {0.f, 0.f, 0.f, 0.f};
    f32x4 acc[4][4];
#pragma unroll
    for (int i = 0; i < 4; ++i)
#pragma unroll
        for (int j = 0; j < 4; ++j)
            acc[i][j] = fzero;

    for (int kt = 0; kt < K_DIM / BK; ++kt) {
        __syncthreads();
#pragma unroll
        for (int r = 0; r < 4; ++r) {
            dma16(gA + (size_t)r * 32 * K_DIM + kt * BK, lA + r * 32 * BK);
            dma16(gB + (size_t)r * 32 * K_DIM + kt * BK, lB + r * 32 * BK);
        }
        __syncthreads();

#pragma unroll
        for (int s = 0; s < 2; ++s) {
            v8bf af[4], bfr[4];
#pragma unroll
            for (int t = 0; t < 4; ++t) af[t]  = *(const v8bf*)(&As[offA[s][t]]);
#pragma unroll
            for (int t = 0; t < 4; ++t) bfr[t] = *(const v8bf*)(&Bs[offB[s][t]]);
#pragma unroll
            for (int i = 0; i < 4; ++i)
#pragma unroll
                for (int j = 0; j < 4; ++j)
                    acc[i][j] = __builtin_amdgcn_mfma_f32_16x16x32_bf16(
                        af[i], bfr[j], acc[i][j], 0, 0, 0);
        }
    }

    float bv[4];
#pragma unroll
    for (int j = 0; j < 4; ++j)
        bv[j] = bias[n0 + wn + j * 16 + lane15];

    __half* outb = (n0 < H_DIM) ? zbuf : hbuf;      // block-uniform
    const int colbase = (n0 & (H_DIM - 1)) + wn + lane15;

#pragma unroll
    for (int i = 0; i < 4; ++i) {
#pragma unroll
        for (int r = 0; r < 4; ++r) {
            const size_t row = (size_t)(m0 + wm + i * 16 + quad * 4 + r);
            __half* p = outb + row * H_DIM + colbase;
#pragma unroll
            for (int j = 0; j < 4; ++j)
                p[j * 16] = __float2half(acc[i][j][r] + bv[j]);
        }
    }
}

// ---------------------------------------------------------------------------
// Gating math (identical in phases 1 and 3).
// a = sigmoid(-z), v = sigmoid(z)*g(hi);  g(x) = x+0.5 (x>=0) else sigmoid(x)
// ---------------------------------------------------------------------------
__device__ __forceinline__ void gate_av(float z, float hi, float& a, float& v)
{
    const float e  = __expf(-z);
    const float sz = 1.0f / (1.0f + e);        // sigmoid(z)
    a = e * sz;                                // sigmoid(-z)
    const float g = (hi >= 0.0f) ? (hi + 0.5f)
                                 : (1.0f / (1.0f + __expf(-hi)));
    v = sz * g;
}

// Phase 1: per-(8-channel group, chunk) affine summary  h_out = A*h_in + B.
// CLEN=16 fully unrolled: all 32 16B loads visible to the scheduler.
__global__ __launch_bounds__(256) void scan_phase1(
    const __half* __restrict__ zbuf, const __half* __restrict__ hbuf,
    float* __restrict__ Aar, float* __restrict__ Bar)
{
    const int idx = blockIdx.x * 256 + threadIdx.x;   // 0..262143
    const int h8  = (idx & 127) << 3;
    const int n   = (idx >> 7) & 7;
    const int c   = idx >> 10;                        // 0..255
    const size_t base = ((size_t)(n * L_SEQ + c * CLEN)) * H_DIM + h8;
    const f32x4* zp = (const f32x4*)(zbuf + base);    // f32x4 == 8 halves
    const f32x4* hp = (const f32x4*)(hbuf + base);

    float A[8], B[8];
#pragma unroll
    for (int j = 0; j < 8; ++j) { A[j] = 1.f; B[j] = 0.f; }

#pragma unroll
    for (int s = 0; s < CLEN; ++s) {
        f32x4 zr = zp[(size_t)s * (H_DIM / 8)];
        f32x4 hr = hp[(size_t)s * (H_DIM / 8)];
        const __half2* z2 = (const __half2*)&zr;
        const __half2* i2 = (const __half2*)&hr;
#pragma unroll
        for (int j = 0; j < 4; ++j) {
            const float2 z  = __half22float2(z2[j]);
            const float2 hi = __half22float2(i2[j]);
            float a, v;
            gate_av(z.x, hi.x, a, v);
            B[2*j]   = fmaf(a, B[2*j],   v);  A[2*j]   *= a;
            gate_av(z.y, hi.y, a, v);
            B[2*j+1] = fmaf(a, B[2*j+1], v);  A[2*j+1] *= a;
        }
    }
    const size_t o = (size_t)c * NCH + n * H_DIM + h8;
    *(f32x4*)(Aar + o)     = *(const f32x4*)&A[0];
    *(f32x4*)(Aar + o + 4) = *(const f32x4*)&A[4];
    *(f32x4*)(Bar + o)     = *(const f32x4*)&B[0];
    *(f32x4*)(Bar + o + 4) = *(const f32x4*)&B[4];
}

// Phase 2: compose NCHUNK chunk summaries per channel, seed with hx (fp32).
// Seeds stored fp16 (<=2.4e-3 absolute, decays within a chunk).
__global__ __launch_bounds__(256) void scan_phase2(
    const float* __restrict__ Aar, const float* __restrict__ Bar,
    const float* __restrict__ hx, __half* __restrict__ seed)
{
    const int ch = blockIdx.x * 256 + threadIdx.x;    // 0..8191
    float carry = hx[ch];
#pragma unroll 8
    for (int c = 0; c < NCHUNK; ++c) {
        seed[c * NCH + ch] = __float2half(carry);
        carry = fmaf(Aar[c * NCH + ch], carry, Bar[c * NCH + ch]);
    }
}

// Phase 3: replay each chunk from its seed; fully unrolled, nontemporal
// stores for the 134 MB out stream (keeps zbuf/hbuf LLC-resident).
__global__ __launch_bounds__(256) void scan_phase3(
    const __half* __restrict__ zbuf, const __half* __restrict__ hbuf,
    const __half* __restrict__ seed, float* __restrict__ out)
{
    const int idx = blockIdx.x * 256 + threadIdx.x;
    const int h8  = (idx & 127) << 3;
    const int n   = (idx >> 7) & 7;
    const int c   = idx >> 10;
    const size_t base = ((size_t)(n * L_SEQ + c * CLEN)) * H_DIM + h8;
    const f32x4* zp = (const f32x4*)(zbuf + base);
    const f32x4* hp = (const f32x4*)(hbuf + base);
    float* op = out + base;

    const size_t so = (size_t)c * NCH + n * H_DIM + h8;
    f32x4 sr = *(const f32x4*)(seed + so);            // 8 fp16 seeds
    const __half2* s2 = (const __half2*)&sr;
    float h0[4], h1[4];
#pragma unroll
    for (int j = 0; j < 2; ++j) {
        const float2 a = __half22float2(s2[j]);
        h0[2*j] = a.x; h0[2*j+1] = a.y;
        const float2 b = __half22float2(s2[2+j]);
        h1[2*j] = b.x; h1[2*j+1] = b.y;
    }

#pragma unroll
    for (int s = 0; s < CLEN; ++s) {
        f32x4 zr = zp[(size_t)s * (H_DIM / 8)];
        f32x4 hr = hp[(size_t)s * (H_DIM / 8)];
        const __half2* z2 = (const __half2*)&zr;
        const __half2* i2 = (const __half2*)&hr;
#pragma unroll
        for (int j = 0; j < 2; ++j) {
            const float2 za = __half22float2(z2[j]);
            const float2 ia = __half22float2(i2[j]);
            float a, v;
            gate_av(za.x, ia.x, a, v);  h0[2*j]   = fmaf(a, h0[2*j],   v);
            gate_av(za.y, ia.y, a, v);  h0[2*j+1] = fmaf(a, h0[2*j+1], v);
            const float2 zb = __half22float2(z2[2+j]);
            const float2 ib = __half22float2(i2[2+j]);
            gate_av(zb.x, ib.x, a, v);  h1[2*j]   = fmaf(a, h1[2*j],   v);
            gate_av(zb.y, ib.y, a, v);  h1[2*j+1] = fmaf(a, h1[2*j+1], v);
        }
        float* pr = op + (size_t)s * H_DIM;
        __builtin_nontemporal_store(*(const f32x4*)h0, (f32x4*)pr);
        __builtin_nontemporal_store(*(const f32x4*)h1, (f32x4*)(pr + 4));
    }
}

// ---------------------------------------------------------------------------
extern "C" void kernel_launch(void* const* d_in, const int* in_sizes, int n_in,
                              void* d_out, int out_size, void* d_ws, size_t ws_size,
                              hipStream_t stream)
{
    const float* X    = (const float*)d_in[0];   // x  (8,4096,1024) fp32
    const float* Wm   = (const float*)d_in[1];   // W  (2048,1024)   fp32
    const float* bias = (const float*)d_in[2];   // b  (2048)        fp32
    const float* hx   = (const float*)d_in[3];   // hx (8,1024)      fp32
    float* out = (float*)d_out;                  // (8,4096,1024)    fp32

    char* ws = (char*)d_ws;
    ushort_t* wb = (ushort_t*)ws;                                  //  4 MiB
    __half* zbuf = (__half*)(ws + (size_t)O_DIM * K_DIM * 2);      // 64 MiB
    __half* hbuf = zbuf + (size_t)M_TOT * H_DIM;                   // 64 MiB
    __half* seed = hbuf + (size_t)M_TOT * H_DIM;                   //  4 MiB

    // d_out (128 MiB) doubles as scratch until phase3 overwrites it:
    //   bytes [0, 64Mi):   x_bf16  (M_TOT*K_DIM*2 B = exactly half)
    //   bytes [64Mi,80Mi): Aar, Bar (NCHUNK*NCH fp32 each, dead after p2)
    // seed must NOT live in d_out: p3 reads it while storing out.
    ushort_t* xb = (ushort_t*)d_out;
    float* Aar = out + (size_t)M_TOT * H_DIM / 2;      // true halfway point
    float* Bar = Aar + (size_t)NCHUNK * NCH;

    cvt_f32_bf16<<<O_DIM * K_DIM / 8 / 256, 256, 0, stream>>>(Wm, wb);
    cvt_f32_bf16<<<M_TOT * K_DIM / 8 / 256, 256, 0, stream>>>(X, xb);

    dim3 ggrid(O_DIM / BN, M_TOT / BM);          // (16, 256): O fast for reuse
    gemm_zh<<<ggrid, 256, 0, stream>>>(xb, wb, bias, zbuf, hbuf);

    const int p13_blocks = (NCH / 8) * NCHUNK / 256;   // 1024
    scan_phase1<<<p13_blocks, 256, 0, stream>>>(zbuf, hbuf, Aar, Bar);
    scan_phase2<<<NCH / 256, 256, 0, stream>>>(Aar, Bar, hx, seed);
    scan_phase3<<<p13_blocks, 256, 0, stream>>>(zbuf, hbuf, seed, out);
}